// Round 20
// baseline (263.832 us; speedup 1.0000x reference)
//
#include <hip/hip_runtime.h>
#include <hip/hip_fp16.h>

// Conv2d 3x3 s1 p1, NCHW fp32: N=32, Cin=256, H=W=56, Cout=256.
// R20 = R10 (best, 161us conv) with 3-tap BATCHED sW staging.
// Identical ordering (stage -> barrier -> compute -> barrier); just 3 taps
// per stage phase: latency exposures 72->24, barriers 144->48.
// kh=g, kw=tl (tap=3g+tl). LDS 36.8KB. fp16, MFMA 16x16x32_f16.

#define NB   32
#define CIN  256
#define HH   56
#define WW   56
#define COUT 256

typedef unsigned short u16;
typedef __attribute__((ext_vector_type(8))) _Float16 f16x8;
typedef __attribute__((ext_vector_type(4))) float    f32x4;

#define XS_ELEMS (32u*58u*58u*256u)          // padded NHWC fp16
#define XS_BYTES ((size_t)XS_ELEMS*2u)
#define WP_ELEMS (256u*2304u)                // [co][tap9][ci256] fp16
#define WP_BYTES ((size_t)WP_ELEMS*2u)
#define WS_NEED  (XS_BYTES + WP_BYTES)

__device__ __forceinline__ void gld16(const u16* g, u16* l) {
    __builtin_amdgcn_global_load_lds(
        (const __attribute__((address_space(1))) void*)g,
        (__attribute__((address_space(3))) void*)l, 16, 0, 0);
}

__device__ __forceinline__ u16 f16_bits(float v) {
    _Float16 h = (_Float16)v;                // RNE
    return *reinterpret_cast<u16*>(&h);
}

// ---- pre-pass 0: zero halo border cells of xs ----
__global__ __launch_bounds__(256) void halo_zero(u16* __restrict__ xh) {
    unsigned i = blockIdx.x*256u + threadIdx.x;   // img*228*32 + cell*32 + g
    if (i >= 32u*228u*32u) return;
    unsigned g    = i & 31u;
    unsigned cell = (i >> 5) % 228u;
    unsigned img  = i / (228u*32u);
    unsigned h, w;
    if      (cell < 58)  { h = 0;                w = cell; }
    else if (cell < 116) { h = 57;               w = cell - 58; }
    else if (cell < 172) { h = 1 + (cell - 116); w = 0; }
    else                 { h = 1 + (cell - 172); w = 57; }
    unsigned o = ((img*58u + h)*58u + w)*256u + g*8u;
    uint4 z = {0u,0u,0u,0u};
    *reinterpret_cast<uint4*>(&xh[o]) = z;
}

// ---- pre-pass 1: x (NCHW f32) -> xs (padded NHWC fp16) ----
__global__ __launch_bounds__(256) void xcvt(const float* __restrict__ x,
                                            u16* __restrict__ xh) {
    __shared__ float tile[32][57];
    const int t  = threadIdx.x;
    const int b  = blockIdx.x;              // n*(8*56) + cg*56 + h
    const int n  = b / (8*56);
    const int cg = (b / 56) % 8;
    const int h  = b % 56;
    const float* src = x + ((size_t)n*CIN + cg*32) * 3136 + (unsigned)h*56;
    #pragma unroll
    for (int k = 0; k < 7; ++k) {           // 32*56 = 1792 = 7*256
        int idx = t + k*256;
        int c = idx / 56, w = idx % 56;
        tile[c][w] = src[(unsigned)c*3136 + w];
    }
    __syncthreads();
    const unsigned obase = (((unsigned)n*58 + h + 1)*58 + 1)*256 + cg*32;
    #pragma unroll
    for (int k = 0; k < 7; ++k) {
        int idx = t + k*256;
        int w = idx / 32, c = idx % 32;
        xh[obase + (unsigned)w*256 + c] = f16_bits(tile[c][w]);
    }
}

// ---- pre-pass 2: w (OIHW f32) -> wp [co][tap][ci] fp16 ----
__global__ __launch_bounds__(256) void wcvt(const float* __restrict__ w,
                                            u16* __restrict__ wp) {
    unsigned i = blockIdx.x*256u + threadIdx.x;
    if (i >= WP_ELEMS) return;
    unsigned co  = i / 2304u;
    unsigned r   = i % 2304u;
    unsigned tap = r >> 8;        // kh*3+kw
    unsigned ci  = r & 255u;
    wp[i] = f16_bits(w[(size_t)co*2304u + ci*9u + tap]);
}

// ---- main conv kernel ----
// Block: 256 thr / 4 waves; tile 128co x 2img x (8x8 sp). Wave: 64co x 64sp.
// MFMA 16x16x32_f16 (HW-verified R9/R10): A row=lane&15 (co), k=(lane>>4)*8+j;
// B col=lane&15 (sp); C/D col=lane&15, row=(lane>>4)*4+reg.
// LDS slot bijection (both arrays): slot(row,g) = (row>>1)*8 + g*2 + (row&1);
// staging inverse: row = (s>>3)*2 + (s&1), g = (s>>1)&3.
// sW holds 3 taps (groups g=0..2 of chunk ck); stage->barrier->compute x3.
__global__ __launch_bounds__(256, 4) void conv_mfma(
    const u16* __restrict__ xs,
    const u16* __restrict__ wp,
    const float* __restrict__ bias, float* __restrict__ y) {
    __shared__ __align__(16) u16 sW[1536*8];   // 3 taps x 512 slots x 16B = 24 KB
    __shared__ __align__(16) u16 sX[800*8];    // 12.8 KB

    const int t    = threadIdx.x;
    const int lane = t & 63, wid = t >> 6;
    const int wc   = wid >> 1;          // co half (0/1)
    const int iwv  = wid & 1;           // image   (0/1)
    const int l15  = lane & 15, kg = lane >> 4;
    const int prb  = l15 >> 3;          // row parity within pair
    const int pc   = l15 & 7;           // patch col

    const int bid  = blockIdx.x;        // (co_t*49 + sp)*16 + nt
    const int co_t = bid / (49*16);
    const int rem  = bid % (49*16);
    const int sp   = rem / 16;
    const int nt   = rem % 16;
    const int h0   = (sp / 7) * 8, w0 = (sp % 7) * 8;
    const int co0  = co_t * 128;
    const int n0   = nt * 2;

    f32x4 acc[4][4];
    #pragma unroll
    for (int m = 0; m < 4; ++m)
        #pragma unroll
        for (int j = 0; j < 4; ++j) acc[m][j] = f32x4{0.f, 0.f, 0.f, 0.f};

    for (int ck = 0; ck < 8; ++ck) {
        for (int g = 0; g < 3; ++g) {
            __syncthreads();   // protect prev group's sW reads (and prev chunk's sX at g==0)

            if (g == 0) {
                // stage sX for chunk ck: 800 slots
                #pragma unroll
                for (int k = 0; k < 4; ++k) {
                    int s = t + k*256;
                    if (s < 800) {
                        int cell = ((s >> 3) << 1) + (s & 1);
                        int gg   = (s >> 1) & 3;
                        int im = cell / 100, r100 = cell % 100;
                        int r = r100 / 10, c = r100 % 10;
                        unsigned go = (((unsigned)(n0+im)*58u + (unsigned)(h0+r))*58u
                                       + (unsigned)(w0+c))*256u
                                      + (unsigned)ck*32u + (unsigned)gg*8u;
                        gld16(xs + go, &sX[(unsigned)s*8u]);
                    }
                }
            }
            // stage sW for taps 3g..3g+2: 1536 slots = 6 loads/thread
            #pragma unroll
            for (int k = 0; k < 6; ++k) {
                int st = t + k*256;            // 0..1535
                int tl = st >> 9;              // tap within group
                int s  = st & 511;
                int co_l = ((s >> 3) << 1) + (s & 1);
                int gg   = (s >> 1) & 3;
                unsigned go = (unsigned)(co0+co_l)*2304u
                              + (unsigned)(g*3 + tl)*256u
                              + (unsigned)ck*32u + (unsigned)gg*8u;
                gld16(wp + go, &sW[(unsigned)st*8u]);
            }
            __syncthreads();   // drains vmcnt(0): staged data visible

            // compute taps tl = 0..2 of this group (kh = g, kw = tl)
            #pragma unroll
            for (int tl = 0; tl < 3; ++tl) {
                f16x8 ah[4], bh[4];
                #pragma unroll
                for (int m = 0; m < 4; ++m) {
                    const int co_r = wc*64 + m*16 + l15;
                    const unsigned aslot = (unsigned)((co_r >> 1)*8 + kg*2 + (co_r & 1));
                    ah[m] = *reinterpret_cast<const f16x8*>(
                        &sW[(unsigned)tl*4096u + aslot*8u]);
                }
                #pragma unroll
                for (int j = 0; j < 4; ++j) {
                    const int cell = iwv*100 + (2*j + prb + g)*10 + pc + tl;
                    const unsigned bslot = (unsigned)((cell >> 1)*8 + kg*2 + (cell & 1));
                    bh[j] = *reinterpret_cast<const f16x8*>(&sX[bslot*8u]);
                }
                #pragma unroll
                for (int m = 0; m < 4; ++m)
                    #pragma unroll
                    for (int j = 0; j < 4; ++j)
                        acc[m][j] = __builtin_amdgcn_mfma_f32_16x16x32_f16(ah[m], bh[j], acc[m][j], 0, 0, 0);
            }
        }
    }

    // ---- epilogue: col=lane&15 (spatial), row=(lane>>4)*4+reg (co) ----
    const int n_img = n0 + iwv;
    #pragma unroll
    for (int m = 0; m < 4; ++m) {
        const int cob = co0 + wc*64 + m*16 + kg*4;
        const float4 bv = *reinterpret_cast<const float4*>(&bias[cob]);
        #pragma unroll
        for (int j = 0; j < 4; ++j) {
            const int pr = 2*j + prb;
            const unsigned yo = ((unsigned)(n_img*COUT + cob)*56u + (unsigned)(h0+pr))*56u
                                + (unsigned)(w0+pc);
            y[yo]         = acc[m][j][0] + bv.x;
            y[yo + 3136u] = acc[m][j][1] + bv.y;
            y[yo + 6272u] = acc[m][j][2] + bv.z;
            y[yo + 9408u] = acc[m][j][3] + bv.w;
        }
    }
}

// ---- fp32 fallback if ws_size is insufficient ----
#define BM 128
#define KC 8
__global__ __launch_bounds__(256, 3) void conv3x3_f32(
    const float* __restrict__ x, const float* __restrict__ wgt,
    const float* __restrict__ bias, float* __restrict__ y) {
    __shared__ float sW[KC * 9][BM];
    __shared__ float sX[KC][10][12];
    const int t = threadIdx.x;
    const int tco = t >> 4, tsp = t & 15;
    const int srow = tsp >> 1, scol0 = (tsp & 1) * 4;
    const int bid = blockIdx.x;
    const int co_t = bid / (49 * NB);
    const int rem = bid % (49 * NB);
    const int sp_t = rem / NB, n = rem % NB;
    const int h0 = (sp_t / 7) * 8, w0 = (sp_t % 7) * 8;
    const int co0 = co_t * BM;
    float acc[8][4];
    #pragma unroll
    for (int r = 0; r < 8; ++r)
        #pragma unroll
        for (int j = 0; j < 4; ++j) acc[r][j] = 0.f;
    const int co_l = t >> 1, half = t & 1;
    for (int ci0 = 0; ci0 < CIN; ci0 += KC) {
        __syncthreads();
        {
            const float4* wsrc = reinterpret_cast<const float4*>(
                wgt + (size_t)(co0 + co_l) * (CIN * 9) + ci0 * 9 + half * 36);
            #pragma unroll
            for (int q = 0; q < 9; ++q) {
                float4 v = wsrc[q];
                const int k0 = half * 36 + q * 4;
                sW[k0 + 0][co_l] = v.x; sW[k0 + 1][co_l] = v.y;
                sW[k0 + 2][co_l] = v.z; sW[k0 + 3][co_l] = v.w;
            }
        }
        for (int idx = t; idx < KC * 100; idx += 256) {
            const int c = idx / 100, r = (idx % 100) / 10, cc = idx % 10;
            const int hh = h0 + r - 1, ww = w0 + cc - 1;
            float v = 0.f;
            if (hh >= 0 && hh < HH && ww >= 0 && ww < WW)
                v = x[(((size_t)n * CIN + (ci0 + c)) * HH + hh) * WW + ww];
            sX[c][r][cc] = v;
        }
        __syncthreads();
        for (int c = 0; c < KC; ++c) {
            #pragma unroll
            for (int kh = 0; kh < 3; ++kh) {
                float xw[8];
                *reinterpret_cast<float4*>(&xw[0]) =
                    *reinterpret_cast<const float4*>(&sX[c][srow + kh][scol0]);
                *reinterpret_cast<float4*>(&xw[4]) =
                    *reinterpret_cast<const float4*>(&sX[c][srow + kh][scol0 + 4]);
                #pragma unroll
                for (int kw = 0; kw < 3; ++kw) {
                    const int kidx = c * 9 + kh * 3 + kw;
                    float wv[8];
                    *reinterpret_cast<float4*>(&wv[0]) =
                        *reinterpret_cast<const float4*>(&sW[kidx][tco * 8]);
                    *reinterpret_cast<float4*>(&wv[4]) =
                        *reinterpret_cast<const float4*>(&sW[kidx][tco * 8 + 4]);
                    #pragma unroll
                    for (int r = 0; r < 8; ++r)
                        #pragma unroll
                        for (int j = 0; j < 4; ++j)
                            acc[r][j] = fmaf(wv[r], xw[kw + j], acc[r][j]);
                }
            }
        }
    }
    const int h = h0 + srow, wc2 = w0 + scol0;
    #pragma unroll
    for (int r = 0; r < 8; ++r) {
        const int co = co0 + tco * 8 + r;
        const float bv = bias[co];
        float4 o;
        o.x = acc[r][0] + bv; o.y = acc[r][1] + bv;
        o.z = acc[r][2] + bv; o.w = acc[r][3] + bv;
        *reinterpret_cast<float4*>(
            &y[(((size_t)n * COUT + co) * HH + h) * WW + wc2]) = o;
    }
}

extern "C" void kernel_launch(void* const* d_in, const int* in_sizes, int n_in,
                              void* d_out, int out_size, void* d_ws, size_t ws_size,
                              hipStream_t stream) {
    const float* x    = (const float*)d_in[0];
    const float* wgt  = (const float*)d_in[1];
    const float* bias = (const float*)d_in[2];
    float* y          = (float*)d_out;

    if (ws_size < WS_NEED) {
        conv3x3_f32<<<2 * 49 * NB, 256, 0, stream>>>(x, wgt, bias, y);
        return;
    }

    u16* xs = (u16*)d_ws;
    u16* wpp = (u16*)((char*)d_ws + XS_BYTES);

    halo_zero<<<(int)((32u*228u*32u + 255u)/256u), 256, 0, stream>>>(xs);
    xcvt<<<32*8*56, 256, 0, stream>>>(x, xs);
    wcvt<<<(int)((WP_ELEMS + 255)/256), 256, 0, stream>>>(wgt, wpp);
    conv_mfma<<<2*49*16, 256, 0, stream>>>(xs, wpp, bias, y);
}

// Round 21
// 185.172 us; speedup vs baseline: 1.4248x; 1.4248x over previous
//
#include <hip/hip_runtime.h>
#include <hip/hip_fp16.h>

// Conv2d 3x3 s1 p1, NCHW fp32: N=32, Cin=256, H=W=56, Cout=256.
// R21 = REVERT to R10 (best: conv 161us, total 185us). Nine schedule/layout
// levers (R11-R20) all regressed; R10's stage->barrier->compute loop is the
// practical optimum of this structure: DS ~108us + MFMA ~57us ~serialized.
// fp16 single (absmax 0.03125 passes), MFMA 16x16x32_f16, bijection slots.

#define NB   32
#define CIN  256
#define HH   56
#define WW   56
#define COUT 256

typedef unsigned short u16;
typedef __attribute__((ext_vector_type(8))) _Float16 f16x8;
typedef __attribute__((ext_vector_type(4))) float    f32x4;

#define XS_ELEMS (32u*58u*58u*256u)          // padded NHWC fp16
#define XS_BYTES ((size_t)XS_ELEMS*2u)
#define WP_ELEMS (256u*2304u)                // [co][tap9][ci256] fp16
#define WP_BYTES ((size_t)WP_ELEMS*2u)
#define WS_NEED  (XS_BYTES + WP_BYTES)

__device__ __forceinline__ void gld16(const u16* g, u16* l) {
    __builtin_amdgcn_global_load_lds(
        (const __attribute__((address_space(1))) void*)g,
        (__attribute__((address_space(3))) void*)l, 16, 0, 0);
}

__device__ __forceinline__ u16 f16_bits(float v) {
    _Float16 h = (_Float16)v;                // RNE
    return *reinterpret_cast<u16*>(&h);
}

// ---- pre-pass 0: zero halo border cells of xs ----
__global__ __launch_bounds__(256) void halo_zero(u16* __restrict__ xh) {
    unsigned i = blockIdx.x*256u + threadIdx.x;   // img*228*32 + cell*32 + g
    if (i >= 32u*228u*32u) return;
    unsigned g    = i & 31u;
    unsigned cell = (i >> 5) % 228u;
    unsigned img  = i / (228u*32u);
    unsigned h, w;
    if      (cell < 58)  { h = 0;                w = cell; }
    else if (cell < 116) { h = 57;               w = cell - 58; }
    else if (cell < 172) { h = 1 + (cell - 116); w = 0; }
    else                 { h = 1 + (cell - 172); w = 57; }
    unsigned o = ((img*58u + h)*58u + w)*256u + g*8u;
    uint4 z = {0u,0u,0u,0u};
    *reinterpret_cast<uint4*>(&xh[o]) = z;
}

// ---- pre-pass 1: x (NCHW f32) -> xs (padded NHWC fp16) ----
__global__ __launch_bounds__(256) void xcvt(const float* __restrict__ x,
                                            u16* __restrict__ xh) {
    __shared__ float tile[32][57];
    const int t  = threadIdx.x;
    const int b  = blockIdx.x;              // n*(8*56) + cg*56 + h
    const int n  = b / (8*56);
    const int cg = (b / 56) % 8;
    const int h  = b % 56;
    const float* src = x + ((size_t)n*CIN + cg*32) * 3136 + (unsigned)h*56;
    #pragma unroll
    for (int k = 0; k < 7; ++k) {           // 32*56 = 1792 = 7*256
        int idx = t + k*256;
        int c = idx / 56, w = idx % 56;
        tile[c][w] = src[(unsigned)c*3136 + w];
    }
    __syncthreads();
    const unsigned obase = (((unsigned)n*58 + h + 1)*58 + 1)*256 + cg*32;
    #pragma unroll
    for (int k = 0; k < 7; ++k) {
        int idx = t + k*256;
        int w = idx / 32, c = idx % 32;
        xh[obase + (unsigned)w*256 + c] = f16_bits(tile[c][w]);
    }
}

// ---- pre-pass 2: w (OIHW f32) -> wp [co][tap][ci] fp16 ----
__global__ __launch_bounds__(256) void wcvt(const float* __restrict__ w,
                                            u16* __restrict__ wp) {
    unsigned i = blockIdx.x*256u + threadIdx.x;
    if (i >= WP_ELEMS) return;
    unsigned co  = i / 2304u;
    unsigned r   = i % 2304u;
    unsigned tap = r >> 8;        // kh*3+kw
    unsigned ci  = r & 255u;
    wp[i] = f16_bits(w[(size_t)co*2304u + ci*9u + tap]);
}

// ---- main conv kernel ----
// Block: 256 thr / 4 waves; tile 128co x 2img x (8x8 sp). Wave: 64co x 64sp.
// MFMA 16x16x32_f16: A row=lane&15 (co), k=(lane>>4)*8+j; B col=lane&15 (sp);
// C/D col=lane&15, row=(lane>>4)*4+reg.  (all HW-verified R3/R9/R10)
// LDS slot bijection (both arrays): slot(row,g) = (row>>1)*8 + g*2 + (row&1);
// staging inverse: row = (s>>3)*2 + (s&1), g = (s>>1)&3.
__global__ __launch_bounds__(256, 4) void conv_mfma(
    const u16* __restrict__ xs,
    const u16* __restrict__ wp,
    const float* __restrict__ bias, float* __restrict__ y) {
    __shared__ __align__(16) u16 sW[512*8];    // 512 slots x 16B = 8 KB
    __shared__ __align__(16) u16 sX[800*8];    // 800 slots x 16B = 12.8 KB

    const int t    = threadIdx.x;
    const int lane = t & 63, wid = t >> 6;
    const int wc   = wid >> 1;          // co half (0/1)
    const int iwv  = wid & 1;           // image   (0/1)
    const int l15  = lane & 15, kg = lane >> 4;
    const int prb  = l15 >> 3;          // row parity within pair
    const int pc   = l15 & 7;           // patch col

    const int bid  = blockIdx.x;        // (co_t*49 + sp)*16 + nt
    const int co_t = bid / (49*16);
    const int rem  = bid % (49*16);
    const int sp   = rem / 16;
    const int nt   = rem % 16;
    const int h0   = (sp / 7) * 8, w0 = (sp % 7) * 8;
    const int co0  = co_t * 128;
    const int n0   = nt * 2;

    f32x4 acc[4][4];
    #pragma unroll
    for (int m = 0; m < 4; ++m)
        #pragma unroll
        for (int j = 0; j < 4; ++j) acc[m][j] = f32x4{0.f, 0.f, 0.f, 0.f};

    for (int ck = 0; ck < 8; ++ck) {
        // stage sX: 800 slots; slot s holds (cell=(s>>3)*2+(s&1), g=(s>>1)&3)
        {
            #pragma unroll
            for (int k = 0; k < 4; ++k) {
                int s = t + k*256;
                if (s < 800) {
                    int cell = ((s >> 3) << 1) + (s & 1);
                    int g    = (s >> 1) & 3;
                    int im = cell / 100, r100 = cell % 100;
                    int r = r100 / 10, c = r100 % 10;
                    unsigned go = (((unsigned)(n0+im)*58u + (unsigned)(h0+r))*58u
                                   + (unsigned)(w0+c))*256u
                                  + (unsigned)ck*32u + (unsigned)g*8u;
                    gld16(xs + go, &sX[(unsigned)s*8u]);
                }
            }
        }
        for (int tap = 0; tap < 9; ++tap) {
            // stage sW: 512 slots; slot s holds (co_l=(s>>3)*2+(s&1), g=(s>>1)&3)
            #pragma unroll
            for (int k = 0; k < 2; ++k) {
                int s = t + k*256;
                int co_l = ((s >> 3) << 1) + (s & 1);
                int g    = (s >> 1) & 3;
                unsigned go = (unsigned)(co0+co_l)*2304u + (unsigned)tap*256u
                              + (unsigned)ck*32u + (unsigned)g*8u;
                gld16(wp + go, &sW[(unsigned)s*8u]);
            }
            __syncthreads();   // drains vmcnt(0): sW (and tap0: sX) landed

            const int kh = tap / 3, kw = tap % 3;
            f16x8 ah[4], bh[4];
            #pragma unroll
            for (int m = 0; m < 4; ++m) {
                const int co_r = wc*64 + m*16 + l15;
                const unsigned aslot = (unsigned)((co_r >> 1)*8 + kg*2 + (co_r & 1));
                ah[m] = *reinterpret_cast<const f16x8*>(&sW[aslot*8u]);
            }
            #pragma unroll
            for (int j = 0; j < 4; ++j) {
                const int cell = iwv*100 + (2*j + prb + kh)*10 + pc + kw;
                const unsigned bslot = (unsigned)((cell >> 1)*8 + kg*2 + (cell & 1));
                bh[j] = *reinterpret_cast<const f16x8*>(&sX[bslot*8u]);
            }
            #pragma unroll
            for (int m = 0; m < 4; ++m)
                #pragma unroll
                for (int j = 0; j < 4; ++j)
                    acc[m][j] = __builtin_amdgcn_mfma_f32_16x16x32_f16(ah[m], bh[j], acc[m][j], 0, 0, 0);
            __syncthreads();   // protect next staging overwrite
        }
    }

    // ---- epilogue: col=lane&15 (spatial), row=(lane>>4)*4+reg (co) ----
    const int n_img = n0 + iwv;
    #pragma unroll
    for (int m = 0; m < 4; ++m) {
        const int cob = co0 + wc*64 + m*16 + kg*4;
        const float4 bv = *reinterpret_cast<const float4*>(&bias[cob]);
        #pragma unroll
        for (int j = 0; j < 4; ++j) {
            const int pr = 2*j + prb;
            const unsigned yo = ((unsigned)(n_img*COUT + cob)*56u + (unsigned)(h0+pr))*56u
                                + (unsigned)(w0+pc);
            y[yo]         = acc[m][j][0] + bv.x;
            y[yo + 3136u] = acc[m][j][1] + bv.y;
            y[yo + 6272u] = acc[m][j][2] + bv.z;
            y[yo + 9408u] = acc[m][j][3] + bv.w;
        }
    }
}

// ---- fp32 fallback if ws_size is insufficient ----
#define BM 128
#define KC 8
__global__ __launch_bounds__(256, 3) void conv3x3_f32(
    const float* __restrict__ x, const float* __restrict__ wgt,
    const float* __restrict__ bias, float* __restrict__ y) {
    __shared__ float sW[KC * 9][BM];
    __shared__ float sX[KC][10][12];
    const int t = threadIdx.x;
    const int tco = t >> 4, tsp = t & 15;
    const int srow = tsp >> 1, scol0 = (tsp & 1) * 4;
    const int bid = blockIdx.x;
    const int co_t = bid / (49 * NB);
    const int rem = bid % (49 * NB);
    const int sp_t = rem / NB, n = rem % NB;
    const int h0 = (sp_t / 7) * 8, w0 = (sp_t % 7) * 8;
    const int co0 = co_t * BM;
    float acc[8][4];
    #pragma unroll
    for (int r = 0; r < 8; ++r)
        #pragma unroll
        for (int j = 0; j < 4; ++j) acc[r][j] = 0.f;
    const int co_l = t >> 1, half = t & 1;
    for (int ci0 = 0; ci0 < CIN; ci0 += KC) {
        __syncthreads();
        {
            const float4* wsrc = reinterpret_cast<const float4*>(
                wgt + (size_t)(co0 + co_l) * (CIN * 9) + ci0 * 9 + half * 36);
            #pragma unroll
            for (int q = 0; q < 9; ++q) {
                float4 v = wsrc[q];
                const int k0 = half * 36 + q * 4;
                sW[k0 + 0][co_l] = v.x; sW[k0 + 1][co_l] = v.y;
                sW[k0 + 2][co_l] = v.z; sW[k0 + 3][co_l] = v.w;
            }
        }
        for (int idx = t; idx < KC * 100; idx += 256) {
            const int c = idx / 100, r = (idx % 100) / 10, cc = idx % 10;
            const int hh = h0 + r - 1, ww = w0 + cc - 1;
            float v = 0.f;
            if (hh >= 0 && hh < HH && ww >= 0 && ww < WW)
                v = x[(((size_t)n * CIN + (ci0 + c)) * HH + hh) * WW + ww];
            sX[c][r][cc] = v;
        }
        __syncthreads();
        for (int c = 0; c < KC; ++c) {
            #pragma unroll
            for (int kh = 0; kh < 3; ++kh) {
                float xw[8];
                *reinterpret_cast<float4*>(&xw[0]) =
                    *reinterpret_cast<const float4*>(&sX[c][srow + kh][scol0]);
                *reinterpret_cast<float4*>(&xw[4]) =
                    *reinterpret_cast<const float4*>(&sX[c][srow + kh][scol0 + 4]);
                #pragma unroll
                for (int kw = 0; kw < 3; ++kw) {
                    const int kidx = c * 9 + kh * 3 + kw;
                    float wv[8];
                    *reinterpret_cast<float4*>(&wv[0]) =
                        *reinterpret_cast<const float4*>(&sW[kidx][tco * 8]);
                    *reinterpret_cast<float4*>(&wv[4]) =
                        *reinterpret_cast<const float4*>(&sW[kidx][tco * 8 + 4]);
                    #pragma unroll
                    for (int r = 0; r < 8; ++r)
                        #pragma unroll
                        for (int j = 0; j < 4; ++j)
                            acc[r][j] = fmaf(wv[r], xw[kw + j], acc[r][j]);
                }
            }
        }
    }
    const int h = h0 + srow, wc2 = w0 + scol0;
    #pragma unroll
    for (int r = 0; r < 8; ++r) {
        const int co = co0 + tco * 8 + r;
        const float bv = bias[co];
        float4 o;
        o.x = acc[r][0] + bv; o.y = acc[r][1] + bv;
        o.z = acc[r][2] + bv; o.w = acc[r][3] + bv;
        *reinterpret_cast<float4*>(
            &y[(((size_t)n * COUT + co) * HH + h) * WW + wc2]) = o;
    }
}

extern "C" void kernel_launch(void* const* d_in, const int* in_sizes, int n_in,
                              void* d_out, int out_size, void* d_ws, size_t ws_size,
                              hipStream_t stream) {
    const float* x    = (const float*)d_in[0];
    const float* wgt  = (const float*)d_in[1];
    const float* bias = (const float*)d_in[2];
    float* y          = (float*)d_out;

    if (ws_size < WS_NEED) {
        conv3x3_f32<<<2 * 49 * NB, 256, 0, stream>>>(x, wgt, bias, y);
        return;
    }

    u16* xs = (u16*)d_ws;
    u16* wpp = (u16*)((char*)d_ws + XS_BYTES);

    halo_zero<<<(int)((32u*228u*32u + 255u)/256u), 256, 0, stream>>>(xs);
    xcvt<<<32*8*56, 256, 0, stream>>>(x, xs);
    wcvt<<<(int)((WP_ELEMS + 255)/256), 256, 0, stream>>>(wgt, wpp);
    conv_mfma<<<2*49*16, 256, 0, stream>>>(xs, wpp, bias, y);
}